// Round 8
// baseline (272.317 us; speedup 1.0000x reference)
//
#include <hip/hip_runtime.h>

// TPLoss: pred [B,N] fp32, labels [B,N] int32 (0/1) -> scalar fp32
//   s = sigmoid(pred); TP = sum(s*l); SP = sum(s); SL = sum(l)
//   denom = 1 - N + SP + SL - 2*TP ;  loss = -mean_b(TP/denom)
//
// Path model after R1-R7:
//   regular VGPR-return reads : 2.65 TB/s (per-CU L1 fill queue)
//   nt VGPR-return reads      : 3.70 TB/s (rate cap, occupancy/depth-invariant)
//   mixing the two            : 3.4 TB/s (in-order TCP: regular stalls block nt)
//   pure writes (fill kernel) : 6.9 TB/s -> fabric has headroom
// R8: the one untested read path — global_load_lds DMA (no VGPR writeback).
// Per-wave triple-buffered pipeline, NO barriers (each wave owns its LDS
// region), fine-grained s_waitcnt vmcnt(8) so 2 chunks stay in flight.

typedef float f4v __attribute__((ext_vector_type(4)));
typedef int   i4v __attribute__((ext_vector_type(4)));

#define BDIM 256
#define ROWS 4096
#define COLS 8192
#define CHUNK 512                   // elements per chunk per wave
#define NCHUNK (COLS / CHUNK)       // 16
#define BUFS 3
#define CHUNK_B (CHUNK * 4)         // 2048 B of pred (and 2048 B of labels)
#define BUF_B (2 * CHUNK_B)         // 4 KB per buffer (pred 2K + labels 2K)
#define WAVE_LDS (BUFS * BUF_B)     // 12 KB per wave -> 48 KB per block

typedef __attribute__((address_space(1))) const void gv_t;
typedef __attribute__((address_space(3))) void lv_t;

__global__ __launch_bounds__(BDIM) void tploss_rows(
    const float* __restrict__ pred,
    const int* __restrict__ labels,
    float* __restrict__ row_out)
{
    __shared__ uint8_t smem[4 * WAVE_LDS];   // 48 KB

    const int tid  = threadIdx.x;
    const int lane = tid & 63;
    const int wv   = tid >> 6;
    const int row  = blockIdx.x * 4 + wv;

    const uint8_t* gp = (const uint8_t*)(pred   + (size_t)row * COLS);
    const uint8_t* gl = (const uint8_t*)(labels + (size_t)row * COLS);
    uint8_t* lbase = smem + wv * WAVE_LDS;   // this wave's private region

    float sp = 0.0f;   // sum sigmoid
    float tp = 0.0f;   // sum sigmoid*label
    int   sl = 0;      // sum label (exact)

    // stage chunk c: 4 DMA instrs (2 pred + 2 labels), each 64 lanes x 16 B.
    // LDS dst is wave-uniform; HW adds lane*16. Global src is per-lane.
    auto stage = [&](int c) {
        const int buf = c % BUFS;
#pragma unroll
        for (int j = 0; j < 2; ++j)
            __builtin_amdgcn_global_load_lds(
                (gv_t*)(gp + (size_t)c * CHUNK_B + j * 1024 + lane * 16),
                (lv_t*)(lbase + buf * BUF_B + j * 1024), 16, 0, 0);
#pragma unroll
        for (int j = 0; j < 2; ++j)
            __builtin_amdgcn_global_load_lds(
                (gv_t*)(gl + (size_t)c * CHUNK_B + j * 1024 + lane * 16),
                (lv_t*)(lbase + buf * BUF_B + CHUNK_B + j * 1024), 16, 0, 0);
    };

    stage(0);
    stage(1);

#pragma unroll
    for (int k = 0; k < NCHUNK; ++k) {
        if (k + 2 < NCHUNK) stage(k + 2);

        // wait until chunk k's 4 DMAs land; leave later chunks in flight
        // (vmcnt encoding: imm = vmcnt | expcnt(7)<<4 | lgkmcnt(15)<<8)
        if (k < NCHUNK - 2)       __builtin_amdgcn_s_waitcnt(0xF78); // vmcnt(8)
        else if (k == NCHUNK - 2) __builtin_amdgcn_s_waitcnt(0xF74); // vmcnt(4)
        else                      __builtin_amdgcn_s_waitcnt(0xF70); // vmcnt(0)
        __builtin_amdgcn_sched_barrier(0);

        const int buf = k % BUFS;
        const uint8_t* pbuf = lbase + buf * BUF_B;

#pragma unroll
        for (int r = 0; r < 2; ++r) {
            f4v v = *(const f4v*)(pbuf + r * 1024 + lane * 16);
            i4v q = *(const i4v*)(pbuf + CHUNK_B + r * 1024 + lane * 16);
            f4v s;
            // sigmoid via v_exp + v_rcp (~2^-21 rel err; rcp(inf)=0 correct limit)
            s.x = __builtin_amdgcn_rcpf(1.0f + __expf(-v.x));
            s.y = __builtin_amdgcn_rcpf(1.0f + __expf(-v.y));
            s.z = __builtin_amdgcn_rcpf(1.0f + __expf(-v.z));
            s.w = __builtin_amdgcn_rcpf(1.0f + __expf(-v.w));
            sp += (s.x + s.y) + (s.z + s.w);
            tp = fmaf(s.x, (float)q.x, tp);
            tp = fmaf(s.y, (float)q.y, tp);
            tp = fmaf(s.z, (float)q.z, tp);
            tp = fmaf(s.w, (float)q.w, tp);
            sl += (q.x + q.y) + (q.z + q.w);
        }
    }

    float slf = (float)sl;

    // wave-64 butterfly; waves are fully independent, no __syncthreads
#pragma unroll
    for (int off = 32; off > 0; off >>= 1) {
        sp  += __shfl_down(sp,  off, 64);
        tp  += __shfl_down(tp,  off, 64);
        slf += __shfl_down(slf, off, 64);
    }

    if (lane == 0) {
        float denom = 1.0f - (float)COLS + sp + slf - 2.0f * tp;
        row_out[row] = tp / denom;
    }
}

__global__ __launch_bounds__(BDIM) void tploss_reduce(
    const float* __restrict__ row_out,
    float* __restrict__ out)
{
    const int tid = threadIdx.x;
    float s = 0.0f;
#pragma unroll
    for (int i = 0; i < ROWS / BDIM; ++i)
        s += row_out[i * BDIM + tid];

#pragma unroll
    for (int off = 32; off > 0; off >>= 1)
        s += __shfl_down(s, off, 64);

    __shared__ float sw[BDIM / 64];
    const int wave = tid >> 6;
    const int lane = tid & 63;
    if (lane == 0) sw[wave] = s;
    __syncthreads();

    if (tid == 0) {
        float tot = (sw[0] + sw[1]) + (sw[2] + sw[3]);
        out[0] = -tot * (1.0f / (float)ROWS);
    }
}

extern "C" void kernel_launch(void* const* d_in, const int* in_sizes, int n_in,
                              void* d_out, int out_size, void* d_ws, size_t ws_size,
                              hipStream_t stream) {
    const float* pred   = (const float*)d_in[0];
    const int*   labels = (const int*)d_in[1];
    float* row_out = (float*)d_ws;   // 4096 floats; fully overwritten each call

    tploss_rows<<<ROWS / 4, BDIM, 0, stream>>>(pred, labels, row_out);
    tploss_reduce<<<1, BDIM, 0, stream>>>(row_out, (float*)d_out);
}

// Round 9
// 247.022 us; speedup vs baseline: 1.1024x; 1.1024x over previous
//
#include <hip/hip_runtime.h>

// TPLoss: pred [B,N] fp32, labels [B,N] int32 (0/1) -> scalar fp32
//   s = sigmoid(pred); TP = sum(s*l); SP = sum(s); SL = sum(l)
//   denom = 1 - N + SP + SL - 2*TP ;  loss = -mean_b(TP/denom)
//
// FINAL (R5 structure, best of 8 experiments). Read-path map measured on
// this chip for 268.4 MB streaming fp32:
//   regular VGPR-return loads : 2.65 TB/s (per-CU L1 fill-queue cap; R1-R4,
//                               invariant to occupancy 25-67% and MLP 2-16)
//   global_load_lds DMA       : 2.76 TB/s (same TCP fill path; R8)
//   nt + regular mixed        : 3.40 TB/s (in-order TCP queue; R7)
//   NONTEMPORAL (L1-bypass)   : 3.70 TB/s <- this kernel (R5; occupancy- and
//                               batch-invariant, R6)
// Writes do 6.9 TB/s (no return); copy ubench 6.29 TB/s is read+write
// combined (~3.15/dir). 3.7 TB/s is the pure-read ceiling; this kernel runs
// at it: 268.4 MB / ~73 us. VALUBusy ~8% -> compute irrelevant.

typedef float f4v __attribute__((ext_vector_type(4)));
typedef int   i4v __attribute__((ext_vector_type(4)));

#define BDIM 256
#define WPB 4              // waves per block, one row each
#define ROWS 4096
#define COLS 8192
#define HALF 16            // float4 chunks per phase (16KB pred / 16KB labels)

__global__ __launch_bounds__(BDIM) void tploss_rows(
    const float* __restrict__ pred,
    const int* __restrict__ labels,
    float* __restrict__ row_out)
{
    const int lane = threadIdx.x & 63;
    const int row  = blockIdx.x * WPB + (threadIdx.x >> 6);

    const f4v* pb = (const f4v*)(pred   + (size_t)row * COLS) + lane;
    const i4v* lb = (const i4v*)(labels + (size_t)row * COLS) + lane;

    float sp = 0.0f;   // sum sigmoid
    float tp = 0.0f;   // sum sigmoid*label
    int   sl = 0;      // sum label (exact)

    for (int h = 0; h < 2; ++h) {
        const f4v* ph = pb + h * HALF * 64;
        const i4v* lh = lb + h * HALF * 64;

        // ---- phase A: pred-only stream, nontemporal (L1-bypass) ----
        f4v s[HALF];
#pragma unroll
        for (int i = 0; i < HALF; ++i) s[i] = __builtin_nontemporal_load(&ph[i * 64]);
#pragma unroll
        for (int i = 0; i < HALF; ++i) asm volatile("" : "+v"(s[i]));  // pin: keep loads batched

#pragma unroll
        for (int i = 0; i < HALF; ++i) {
            f4v v = s[i];
            f4v r;
            // sigmoid via v_exp + v_rcp (~2^-21 rel err; rcp(inf)=0 correct limit)
            r.x = __builtin_amdgcn_rcpf(1.0f + __expf(-v.x));
            r.y = __builtin_amdgcn_rcpf(1.0f + __expf(-v.y));
            r.z = __builtin_amdgcn_rcpf(1.0f + __expf(-v.z));
            r.w = __builtin_amdgcn_rcpf(1.0f + __expf(-v.w));
            sp += (r.x + r.y) + (r.z + r.w);
            s[i] = r;  // hold sigmoids for phase B
        }

        // ---- phase B: label-only stream, nontemporal, 2 batches of 8 ----
#pragma unroll
        for (int b = 0; b < 2; ++b) {
            i4v q[8];
#pragma unroll
            for (int i = 0; i < 8; ++i) q[i] = __builtin_nontemporal_load(&lh[(b * 8 + i) * 64]);
#pragma unroll
            for (int i = 0; i < 8; ++i) asm volatile("" : "+v"(q[i]));

#pragma unroll
            for (int i = 0; i < 8; ++i) {
                f4v r = s[b * 8 + i];
                tp = fmaf(r.x, (float)q[i].x, tp);
                tp = fmaf(r.y, (float)q[i].y, tp);
                tp = fmaf(r.z, (float)q[i].z, tp);
                tp = fmaf(r.w, (float)q[i].w, tp);
                sl += (q[i].x + q[i].y) + (q[i].z + q[i].w);
            }
        }
    }

    float slf = (float)sl;

    // wave-64 butterfly; no LDS, no __syncthreads
#pragma unroll
    for (int off = 32; off > 0; off >>= 1) {
        sp  += __shfl_down(sp,  off, 64);
        tp  += __shfl_down(tp,  off, 64);
        slf += __shfl_down(slf, off, 64);
    }

    if (lane == 0) {
        float denom = 1.0f - (float)COLS + sp + slf - 2.0f * tp;
        row_out[row] = tp / denom;   // one plain store per row, no atomics
    }
}

__global__ __launch_bounds__(BDIM) void tploss_reduce(
    const float* __restrict__ row_out,
    float* __restrict__ out)
{
    const int tid = threadIdx.x;
    float s = 0.0f;
#pragma unroll
    for (int i = 0; i < ROWS / BDIM; ++i)
        s += row_out[i * BDIM + tid];

#pragma unroll
    for (int off = 32; off > 0; off >>= 1)
        s += __shfl_down(s, off, 64);

    __shared__ float sw[BDIM / 64];
    const int wave = tid >> 6;
    const int lane = tid & 63;
    if (lane == 0) sw[wave] = s;
    __syncthreads();

    if (tid == 0) {
        float tot = (sw[0] + sw[1]) + (sw[2] + sw[3]);
        out[0] = -tot * (1.0f / (float)ROWS);
    }
}

extern "C" void kernel_launch(void* const* d_in, const int* in_sizes, int n_in,
                              void* d_out, int out_size, void* d_ws, size_t ws_size,
                              hipStream_t stream) {
    const float* pred   = (const float*)d_in[0];
    const int*   labels = (const int*)d_in[1];
    float* row_out = (float*)d_ws;   // 4096 floats; fully overwritten each call

    tploss_rows<<<ROWS / WPB, BDIM, 0, stream>>>(pred, labels, row_out);
    tploss_reduce<<<1, BDIM, 0, stream>>>(row_out, (float*)d_out);
}